// Round 9
// baseline (176.180 us; speedup 1.0000x reference)
//
#include <hip/hip_runtime.h>

typedef __attribute__((ext_vector_type(8))) short short8;
typedef __attribute__((ext_vector_type(16))) float f32x16;

#define MFMA32 __builtin_amdgcn_mfma_f32_32x32x16_bf16

__device__ __forceinline__ unsigned short f2bf(float f) {
  unsigned int u = __float_as_uint(f);
  u += 0x7fffu + ((u >> 16) & 1u);
  return (unsigned short)(u >> 16);
}

// Pre-pack the 6 weight matrices fp32 [k][n] -> bf16 MFMA-fragment order:
// wt[(((s*6 + g)*8 + c)*64 + l)*8 + j] = G_g[k][n]
//   with k = s*16 + (l>>5)*8 + j, n = c*32 + (l&31)
// One (slab,gate,chunk) brick = 1 KB = one wave's B-fragment, contiguous.
__global__ __launch_bounds__(256) void wprep(
    const float* __restrict__ Wu, const float* __restrict__ Wr, const float* __restrict__ Wh,
    const float* __restrict__ Uu, const float* __restrict__ Ur, const float* __restrict__ Uh,
    unsigned short* __restrict__ wt) {
  int idx = blockIdx.x * 256 + threadIdx.x;   // 0 .. 6*65536-1
  int j = idx & 7;
  int l = (idx >> 3) & 63;
  int c = (idx >> 9) & 7;
  int sg = idx >> 12;
  int g = sg % 6;
  int s = sg / 6;
  int k = s * 16 + (l >> 5) * 8 + j;
  int n = c * 32 + (l & 31);
  const float* src = (g == 0) ? Wu : (g == 1) ? Wr : (g == 2) ? Wh
                   : (g == 3) ? Uu : (g == 4) ? Ur : Uh;
  wt[idx] = f2bf(src[k * 256 + n]);
}

// Fused AUGRU. Block = 256 thr (4 waves), stripe = 128 rows, all 256 cols
// as two sequential 128-col halves. Wave w: all 128 rows (4 m-frags) x 32
// cols of the current half. acc = 16 x f32x16 = 256 regs (1 wave/SIMD).
// Each W fragment feeds 4 MFMAs -> weight L2 traffic 393 MB total (vs 1.57GB
// at BM=64). x/h tiles in LDS, fragment-ordered (conflict-free b128 reads):
// element (r,k) at brick(s=k>>4, m=r>>5)*1024 + (slot^(s&7))*16 + (k&7)*2,
// slot = (r&31)|(((k>>3)&1)<<5); lane l of slab s reads (l^(s&7))*16.
__global__ __launch_bounds__(256, 1) void augru_main(
    const float* __restrict__ x, const float* __restrict__ h1,
    const float* __restrict__ a, const unsigned short* __restrict__ wt,
    const float* __restrict__ bu, const float* __restrict__ br,
    const float* __restrict__ bh, float* __restrict__ out) {
  extern __shared__ char smem[];
  char* lX = smem;                       // 65536 B x tile
  char* lH = smem + 65536;               // 65536 B h tile
  float* a_s = (float*)(smem + 131072);  // 128 floats

  const int tid = threadIdx.x;
  const int l   = tid & 63;
  const int wid = tid >> 6;            // 0..3 -> col chunk within half
  const int fq  = l >> 5;
  const long rowbase = (long)blockIdx.x * 128;
  const char* wtb = (const char*)wt + (l << 4);
  const float* xsrc = x + rowbase * 256;
  const float* hsrc = h1 + rowbase * 256;

#define STG_ISS(SRC, BUF, K)                                                \
  { _Pragma("unroll")                                                       \
    for (int ii = 0; ii < 8; ++ii)                                          \
      BUF[ii] = ((const float4*)(SRC))[(K) * 2048 + ii * 256 + tid]; }

#define STG_WR(DST, BUF, K)                                                 \
  { _Pragma("unroll")                                                       \
    for (int ii = 0; ii < 8; ++ii) {                                        \
      int f_ = (K) * 2048 + ii * 256 + tid;                                 \
      int row_ = f_ >> 6;                                                   \
      int k0_ = (f_ & 63) << 2;                                             \
      int s__ = k0_ >> 4;                                                   \
      int slt_ = (row_ & 31) | (((k0_ >> 3) & 1) << 5);                     \
      ushort4 b_;                                                           \
      b_.x = f2bf(BUF[ii].x); b_.y = f2bf(BUF[ii].y);                       \
      b_.z = f2bf(BUF[ii].z); b_.w = f2bf(BUF[ii].w);                       \
      *(ushort4*)((DST) + (((s__ << 2) | (row_ >> 5)) << 10)                \
                  + ((slt_ ^ (s__ & 7)) << 4) + ((k0_ & 7) << 1)) = b_;     \
    } }

  // ---- prologue: stage x tile (dual-buffered batches); W ring; a_s ----
  float4 sb[8], sc[8];
  STG_ISS(xsrc, sb, 0)
  STG_ISS(xsrc, sc, 1)
  short8 W[2][3];
  {
    const long r0 = ((long)wid << 10);
    const long r1 = ((long)(1 * 6) << 13) + ((long)wid << 10);
    W[0][0] = *(const short8*)(wtb + r0);
    W[0][1] = *(const short8*)(wtb + r0 + 8192);
    W[0][2] = *(const short8*)(wtb + r0 + 16384);
    W[1][0] = *(const short8*)(wtb + r1);
    W[1][1] = *(const short8*)(wtb + r1 + 8192);
    W[1][2] = *(const short8*)(wtb + r1 + 16384);
  }
  if (tid < 128) a_s[tid] = a[rowbase + tid];
  STG_WR(lX, sb, 0)
  STG_ISS(xsrc, sb, 2)
  STG_WR(lX, sc, 1)
  STG_ISS(xsrc, sc, 3)
  STG_WR(lX, sb, 2)
  STG_WR(lX, sc, 3)
  __syncthreads();

  f32x16 accU[4] = {}, accR[4] = {}, accXH[4] = {}, accHH[4] = {};
  const int c0 = wid, c1 = wid + 4;

#define SLAB(S, LT, GB, CH, NGB, NCH, ACC2)                                 \
  {                                                                         \
    const int sl4_ = ((l ^ ((S) & 7)) << 4);                                \
    const char* ab_ = (LT) + ((S) << 12);                                   \
    short8 a0_ = *(const short8*)(ab_ + sl4_);                              \
    short8 a1_ = *(const short8*)(ab_ + 1024 + sl4_);                       \
    short8 a2_ = *(const short8*)(ab_ + 2048 + sl4_);                       \
    short8 a3_ = *(const short8*)(ab_ + 3072 + sl4_);                       \
    accU[0] = MFMA32(a0_, W[(S) & 1][0], accU[0], 0, 0, 0);                 \
    accR[0] = MFMA32(a0_, W[(S) & 1][1], accR[0], 0, 0, 0);                 \
    ACC2[0] = MFMA32(a0_, W[(S) & 1][2], ACC2[0], 0, 0, 0);                 \
    accU[1] = MFMA32(a1_, W[(S) & 1][0], accU[1], 0, 0, 0);                 \
    accR[1] = MFMA32(a1_, W[(S) & 1][1], accR[1], 0, 0, 0);                 \
    ACC2[1] = MFMA32(a1_, W[(S) & 1][2], ACC2[1], 0, 0, 0);                 \
    accU[2] = MFMA32(a2_, W[(S) & 1][0], accU[2], 0, 0, 0);                 \
    accR[2] = MFMA32(a2_, W[(S) & 1][1], accR[2], 0, 0, 0);                 \
    ACC2[2] = MFMA32(a2_, W[(S) & 1][2], ACC2[2], 0, 0, 0);                 \
    accU[3] = MFMA32(a3_, W[(S) & 1][0], accU[3], 0, 0, 0);                 \
    accR[3] = MFMA32(a3_, W[(S) & 1][1], accR[3], 0, 0, 0);                 \
    ACC2[3] = MFMA32(a3_, W[(S) & 1][2], ACC2[3], 0, 0, 0);                 \
    const long ro_ = ((S) < 14)                                             \
        ? (((long)(((S) + 2) * 6 + (GB)) << 13) + ((long)(CH) << 10))       \
        : (((long)(((S) - 14) * 6 + (NGB)) << 13) + ((long)(NCH) << 10));   \
    W[(S) & 1][0] = *(const short8*)(wtb + ro_);                            \
    W[(S) & 1][1] = *(const short8*)(wtb + ro_ + 8192);                     \
    W[(S) & 1][2] = *(const short8*)(wtb + ro_ + 16384);                    \
  }

#define EPILOGUE(HF)                                                        \
  {                                                                         \
    const int n_ = (((HF) * 4 + wid) << 5) + (l & 31);                      \
    const float vbu = bu[n_], vbr = br[n_], vbh = bh[n_];                   \
    const float* hcol = h1 + rowbase * 256 + n_;                            \
    float* ocol = out + rowbase * 256 + n_;                                 \
    _Pragma("unroll")                                                       \
    for (int mm = 0; mm < 4; ++mm) {                                        \
      float hE[16];                                                         \
      _Pragma("unroll")                                                     \
      for (int j = 0; j < 16; ++j) {                                        \
        const int rl = mm * 32 + (j & 3) + ((j >> 2) << 3) + (fq << 2);     \
        hE[j] = hcol[(long)rl * 256];                                       \
      }                                                                     \
      _Pragma("unroll")                                                     \
      for (int j = 0; j < 16; ++j) {                                        \
        const int rl = mm * 32 + (j & 3) + ((j >> 2) << 3) + (fq << 2);     \
        const float pu = accU[mm][j] + vbu;                                 \
        const float pr = accR[mm][j] + vbr;                                 \
        const float uu = __builtin_amdgcn_rcpf(1.f + __expf(-pu));          \
        const float rr = __builtin_amdgcn_rcpf(1.f + __expf(-pr));          \
        const float cc = fmaf(rr, accHH[mm][j], accXH[mm][j]) + vbh;        \
        const float tt = __builtin_amdgcn_rcpf(1.f + __expf(-2.f * cc));    \
        const float th = fmaf(2.f, tt, -1.f);                               \
        const float uh = a_s[rl] * uu;                                      \
        const float h1v = hE[j];                                            \
        ocol[(long)rl * 256] = fmaf(uh, th - h1v, h1v);                     \
      }                                                                     \
    }                                                                       \
  }

  // ---- X0: x-tile, gates 0-2, chunk c0; h tile staged via hooks ----
  SLAB(0, lX, 0, c0, 3, c0, accXH)
  STG_ISS(hsrc, sb, 0)
  SLAB(1, lX, 0, c0, 3, c0, accXH)
  SLAB(2, lX, 0, c0, 3, c0, accXH)
  SLAB(3, lX, 0, c0, 3, c0, accXH)
  SLAB(4, lX, 0, c0, 3, c0, accXH)
  STG_WR(lH, sb, 0)
  STG_ISS(hsrc, sb, 1)
  SLAB(5, lX, 0, c0, 3, c0, accXH)
  SLAB(6, lX, 0, c0, 3, c0, accXH)
  SLAB(7, lX, 0, c0, 3, c0, accXH)
  SLAB(8, lX, 0, c0, 3, c0, accXH)
  STG_WR(lH, sb, 1)
  STG_ISS(hsrc, sb, 2)
  SLAB(9, lX, 0, c0, 3, c0, accXH)
  SLAB(10, lX, 0, c0, 3, c0, accXH)
  SLAB(11, lX, 0, c0, 3, c0, accXH)
  SLAB(12, lX, 0, c0, 3, c0, accXH)
  STG_WR(lH, sb, 2)
  STG_ISS(hsrc, sb, 3)
  SLAB(13, lX, 0, c0, 3, c0, accXH)
  SLAB(14, lX, 0, c0, 3, c0, accXH)
  SLAB(15, lX, 0, c0, 3, c0, accXH)
  STG_WR(lH, sb, 3)
  __syncthreads();

  // ---- H0: h-tile, gates 3-5, chunk c0; roll ring into X1 (c1) ----
  SLAB(0, lH, 3, c0, 0, c1, accHH)
  SLAB(1, lH, 3, c0, 0, c1, accHH)
  SLAB(2, lH, 3, c0, 0, c1, accHH)
  SLAB(3, lH, 3, c0, 0, c1, accHH)
  SLAB(4, lH, 3, c0, 0, c1, accHH)
  SLAB(5, lH, 3, c0, 0, c1, accHH)
  SLAB(6, lH, 3, c0, 0, c1, accHH)
  SLAB(7, lH, 3, c0, 0, c1, accHH)
  SLAB(8, lH, 3, c0, 0, c1, accHH)
  SLAB(9, lH, 3, c0, 0, c1, accHH)
  SLAB(10, lH, 3, c0, 0, c1, accHH)
  SLAB(11, lH, 3, c0, 0, c1, accHH)
  SLAB(12, lH, 3, c0, 0, c1, accHH)
  SLAB(13, lH, 3, c0, 0, c1, accHH)
  SLAB(14, lH, 3, c0, 0, c1, accHH)
  SLAB(15, lH, 3, c0, 0, c1, accHH)

  EPILOGUE(0)

  {
    const f32x16 fz = {};
#pragma unroll
    for (int mm = 0; mm < 4; ++mm) {
      accU[mm] = fz; accR[mm] = fz; accXH[mm] = fz; accHH[mm] = fz;
    }
  }

  // ---- X1: x-tile, gates 0-2, chunk c1; roll into H1 (c1) ----
  SLAB(0, lX, 0, c1, 3, c1, accXH)
  SLAB(1, lX, 0, c1, 3, c1, accXH)
  SLAB(2, lX, 0, c1, 3, c1, accXH)
  SLAB(3, lX, 0, c1, 3, c1, accXH)
  SLAB(4, lX, 0, c1, 3, c1, accXH)
  SLAB(5, lX, 0, c1, 3, c1, accXH)
  SLAB(6, lX, 0, c1, 3, c1, accXH)
  SLAB(7, lX, 0, c1, 3, c1, accXH)
  SLAB(8, lX, 0, c1, 3, c1, accXH)
  SLAB(9, lX, 0, c1, 3, c1, accXH)
  SLAB(10, lX, 0, c1, 3, c1, accXH)
  SLAB(11, lX, 0, c1, 3, c1, accXH)
  SLAB(12, lX, 0, c1, 3, c1, accXH)
  SLAB(13, lX, 0, c1, 3, c1, accXH)
  SLAB(14, lX, 0, c1, 3, c1, accXH)
  SLAB(15, lX, 0, c1, 3, c1, accXH)

  // ---- H1: h-tile, gates 3-5, chunk c1; rollover loads harmless ----
  SLAB(0, lH, 3, c1, 0, c0, accHH)
  SLAB(1, lH, 3, c1, 0, c0, accHH)
  SLAB(2, lH, 3, c1, 0, c0, accHH)
  SLAB(3, lH, 3, c1, 0, c0, accHH)
  SLAB(4, lH, 3, c1, 0, c0, accHH)
  SLAB(5, lH, 3, c1, 0, c0, accHH)
  SLAB(6, lH, 3, c1, 0, c0, accHH)
  SLAB(7, lH, 3, c1, 0, c0, accHH)
  SLAB(8, lH, 3, c1, 0, c0, accHH)
  SLAB(9, lH, 3, c1, 0, c0, accHH)
  SLAB(10, lH, 3, c1, 0, c0, accHH)
  SLAB(11, lH, 3, c1, 0, c0, accHH)
  SLAB(12, lH, 3, c1, 0, c0, accHH)
  SLAB(13, lH, 3, c1, 0, c0, accHH)
  SLAB(14, lH, 3, c1, 0, c0, accHH)
  SLAB(15, lH, 3, c1, 0, c0, accHH)

  EPILOGUE(1)

#undef SLAB
#undef EPILOGUE
#undef STG_ISS
#undef STG_WR
}

extern "C" void kernel_launch(void* const* d_in, const int* in_sizes, int n_in,
                              void* d_out, int out_size, void* d_ws, size_t ws_size,
                              hipStream_t stream) {
  const float* x  = (const float*)d_in[0];
  const float* h1 = (const float*)d_in[1];
  const float* a  = (const float*)d_in[2];
  const float* Wu = (const float*)d_in[3];
  const float* Uu = (const float*)d_in[4];
  const float* bu = (const float*)d_in[5];
  const float* Wr = (const float*)d_in[6];
  const float* Ur = (const float*)d_in[7];
  const float* br = (const float*)d_in[8];
  const float* Wh = (const float*)d_in[9];
  const float* Uh = (const float*)d_in[10];
  const float* bh = (const float*)d_in[11];
  unsigned short* wt = (unsigned short*)d_ws;   // 16 slabs x 48 KB = 768 KB

  wprep<<<1536, 256, 0, stream>>>(Wu, Wr, Wh, Uu, Ur, Uh, wt);

  const int lds_bytes = 131072 + 512;
  hipFuncSetAttribute((const void*)augru_main,
                      hipFuncAttributeMaxDynamicSharedMemorySize, lds_bytes);

  const int rows = in_sizes[0] / 256;           // 65536
  augru_main<<<rows / 128, 256, lds_bytes, stream>>>(x, h1, a, wt, bu, br, bh,
                                                     (float*)d_out);
}

// Round 10
// 106.036 us; speedup vs baseline: 1.6615x; 1.6615x over previous
//
#include <hip/hip_runtime.h>

typedef __attribute__((ext_vector_type(8))) short short8;
typedef __attribute__((ext_vector_type(16))) float f32x16;

#define MFMA32 __builtin_amdgcn_mfma_f32_32x32x16_bf16

__device__ __forceinline__ unsigned short f2bf(float f) {
  unsigned int u = __float_as_uint(f);
  u += 0x7fffu + ((u >> 16) & 1u);
  return (unsigned short)(u >> 16);
}

// Pre-pack the 6 weight matrices fp32 [k][n] -> bf16 MFMA-fragment order:
// wt[(((s*6 + g)*8 + c)*64 + l)*8 + j] = G_g[k][n]
//   with k = s*16 + (l>>5)*8 + j, n = c*32 + (l&31)
// One (slab,gate,chunk) brick = 1 KB = one wave's B-fragment, contiguous.
__global__ __launch_bounds__(256) void wprep(
    const float* __restrict__ Wu, const float* __restrict__ Wr, const float* __restrict__ Wh,
    const float* __restrict__ Uu, const float* __restrict__ Ur, const float* __restrict__ Uh,
    unsigned short* __restrict__ wt) {
  int idx = blockIdx.x * 256 + threadIdx.x;   // 0 .. 6*65536-1
  int j = idx & 7;
  int l = (idx >> 3) & 63;
  int c = (idx >> 9) & 7;
  int sg = idx >> 12;
  int g = sg % 6;
  int s = sg / 6;
  int k = s * 16 + (l >> 5) * 8 + j;
  int n = c * 32 + (l & 31);
  const float* src = (g == 0) ? Wu : (g == 1) ? Wr : (g == 2) ? Wh
                   : (g == 3) ? Uu : (g == 4) ? Ur : Uh;
  wt[idx] = f2bf(src[k * 256 + n]);
}

// Fused AUGRU. Block = 512 thr (8 waves), tile 64 rows x 256 cols.
// Wave w owns cols [32w,32w+32), all 64 rows, mfma 32x32x16, acc 8 x f32x16.
// x/h tiles in LDS in FRAGMENT-BRICK order: [slab16][frag2][lane64][16B] --
// lane l reads byte l*16 of its brick = conflict-free ds_read_b128.
// A-frags prefetched 1 slab ahead; W ring depth 3 refilled before consume;
// waves 4-7 traverse slabs XOR 8 (anti-phase with waves 0-3 on each SIMD).
__global__ __launch_bounds__(512, 2) void augru_main(
    const float* __restrict__ x, const float* __restrict__ h1,
    const float* __restrict__ a, const unsigned short* __restrict__ wt,
    const float* __restrict__ bu, const float* __restrict__ br,
    const float* __restrict__ bh, float* __restrict__ out) {
  __shared__ char lX[32768];
  __shared__ char lH[32768];
  __shared__ float a_s[64];

  const int tid = threadIdx.x;
  const int l   = tid & 63;
  const int wid = tid >> 6;            // 0..7 -> 32-col chunk
  const int fq  = l >> 5;
  const long rowbase = (long)blockIdx.x * 64;
  const int n = wid * 32 + (l & 31);
  const int stag = (wid & 4) << 1;     // 0 for waves 0-3, 8 for waves 4-7
  const char* wb = (const char*)wt + (wid << 10) + (l << 4);
#define WOFF(SG) ((long)(SG) << 13)

  const float* xsrc = x + rowbase * 256;
  const float* hsrc = h1 + rowbase * 256;

  // ---- issue x tile loads ----
  float4 xv[8];
#pragma unroll
  for (int i = 0; i < 8; ++i) xv[i] = ((const float4*)xsrc)[i * 512 + tid];

  // ---- W ring init: positions 0,1 (slabs 0^stag, 1^stag, x-gates) ----
  short8 W[3][3];
  {
    const long r0 = WOFF((0 ^ stag) * 6);
    const long r1 = WOFF((1 ^ stag) * 6);
    W[0][0] = *(const short8*)(wb + r0);
    W[0][1] = *(const short8*)(wb + r0 + 8192);
    W[0][2] = *(const short8*)(wb + r0 + 16384);
    W[1][0] = *(const short8*)(wb + r1);
    W[1][1] = *(const short8*)(wb + r1 + 8192);
    W[1][2] = *(const short8*)(wb + r1 + 16384);
  }

  // ---- issue first half of h tile loads ----
  float4 hv[8];
#pragma unroll
  for (int i = 0; i < 4; ++i) hv[i] = ((const float4*)hsrc)[i * 512 + tid];

  const float vbu = bu[n], vbr = br[n], vbh = bh[n];
  if (tid < 64) a_s[tid] = a[rowbase + tid];

  // ---- tile write in fragment-brick order ----
  // float4 item f: row r=f>>6, kq=f&63 (k0=4kq): slab=kq>>2,
  // lane=(r&31)|(((kq>>1)&1)<<5), byte=(kq&1)*8, frag=r>>5.
#define TWRITE(DST, V, I)                                                   \
  {                                                                         \
    const int f_ = (I) * 512 + tid;                                         \
    const int r_ = f_ >> 6;                                                 \
    const int kq_ = f_ & 63;                                                \
    const int addr_ = ((kq_ >> 2) << 11) + ((r_ >> 5) << 10)                \
        + ((((r_ & 31) | (((kq_ >> 1) & 1) << 5))) << 4) + ((kq_ & 1) << 3);\
    ushort4 b_;                                                             \
    b_.x = f2bf((V).x); b_.y = f2bf((V).y);                                 \
    b_.z = f2bf((V).z); b_.w = f2bf((V).w);                                 \
    *(ushort4*)((DST) + addr_) = b_;                                        \
  }

#pragma unroll
  for (int i = 0; i < 8; ++i) TWRITE(lX, xv[i], i)
  __syncthreads();   // lX ready

  f32x16 accU0 = {}, accU1 = {}, accR0 = {}, accR1 = {};
  f32x16 accXH0 = {}, accXH1 = {}, accHH0 = {}, accHH1 = {};

  short8 aF[2][2];
  aF[0][0] = *(const short8*)(lX + (stag << 11) + (l << 4));
  aF[0][1] = *(const short8*)(lX + (stag << 11) + 1024 + (l << 4));

  // ---- x-pass: global positions 0..15, slab = p^stag, gates 0-2 ----
#pragma unroll
  for (int p = 0; p < 16; ++p) {
    if (p < 15) {   // A prefetch next slab
      const int spn = (p + 1) ^ stag;
      aF[(p + 1) & 1][0] = *(const short8*)(lX + (spn << 11) + (l << 4));
      aF[(p + 1) & 1][1] = *(const short8*)(lX + (spn << 11) + 1024 + (l << 4));
    }
    {   // W ring refill for position p+2 (rolls into h-gates at q>=16)
      const int q = p + 2;
      const long ro = (q < 16) ? WOFF((q ^ stag) * 6)
                               : WOFF(((q - 16) ^ stag) * 6 + 3);
      W[q % 3][0] = *(const short8*)(wb + ro);
      W[q % 3][1] = *(const short8*)(wb + ro + 8192);
      W[q % 3][2] = *(const short8*)(wb + ro + 16384);
    }
    const short8 a0 = aF[p & 1][0];
    const short8 a1 = aF[p & 1][1];
    accU0  = MFMA32(a0, W[p % 3][0], accU0, 0, 0, 0);
    accU1  = MFMA32(a1, W[p % 3][0], accU1, 0, 0, 0);
    accR0  = MFMA32(a0, W[p % 3][1], accR0, 0, 0, 0);
    accR1  = MFMA32(a1, W[p % 3][1], accR1, 0, 0, 0);
    accXH0 = MFMA32(a0, W[p % 3][2], accXH0, 0, 0, 0);
    accXH1 = MFMA32(a1, W[p % 3][2], accXH1, 0, 0, 0);
    if (p == 4) {
#pragma unroll
      for (int i = 4; i < 8; ++i) hv[i] = ((const float4*)hsrc)[i * 512 + tid];
    }
    if (p == 8) {
      TWRITE(lH, hv[0], 0) TWRITE(lH, hv[1], 1)
      TWRITE(lH, hv[2], 2) TWRITE(lH, hv[3], 3)
    }
    if (p == 12) {
      TWRITE(lH, hv[4], 4) TWRITE(lH, hv[5], 5)
      TWRITE(lH, hv[6], 6) TWRITE(lH, hv[7], 7)
    }
  }
  __syncthreads();   // lH ready

  aF[0][0] = *(const short8*)(lH + (stag << 11) + (l << 4));
  aF[0][1] = *(const short8*)(lH + (stag << 11) + 1024 + (l << 4));

  // ---- h-pass: global positions 16..31, slab = p^stag, gates 3-5 ----
#pragma unroll
  for (int p = 0; p < 16; ++p) {
    if (p < 15) {
      const int spn = (p + 1) ^ stag;
      aF[(p + 1) & 1][0] = *(const short8*)(lH + (spn << 11) + (l << 4));
      aF[(p + 1) & 1][1] = *(const short8*)(lH + (spn << 11) + 1024 + (l << 4));
    }
    if (p < 14) {
      const int q = p + 2;
      const long ro = WOFF((q ^ stag) * 6 + 3);
      const int sl_w = (q + 16) % 3;
      W[sl_w][0] = *(const short8*)(wb + ro);
      W[sl_w][1] = *(const short8*)(wb + ro + 8192);
      W[sl_w][2] = *(const short8*)(wb + ro + 16384);
    }
    const short8 a0 = aF[p & 1][0];
    const short8 a1 = aF[p & 1][1];
    const int sl = (p + 16) % 3;
    accU0  = MFMA32(a0, W[sl][0], accU0, 0, 0, 0);
    accU1  = MFMA32(a1, W[sl][0], accU1, 0, 0, 0);
    accR0  = MFMA32(a0, W[sl][1], accR0, 0, 0, 0);
    accR1  = MFMA32(a1, W[sl][1], accR1, 0, 0, 0);
    accHH0 = MFMA32(a0, W[sl][2], accHH0, 0, 0, 0);
    accHH1 = MFMA32(a1, W[sl][2], accHH1, 0, 0, 0);
  }

  // ---- epilogue: coalesced fp32 h1 re-read (L2-hot), gates, blend ----
  const float* hcol = h1 + rowbase * 256 + n;
  float* ocol = out + rowbase * 256 + n;
  float hE0[16], hE1[16];
#pragma unroll
  for (int g8 = 0; g8 < 4; ++g8)
#pragma unroll
    for (int j = 0; j < 4; ++j) {
      const int rl = g8 * 8 + fq * 4 + j;
      hE0[g8 * 4 + j] = hcol[(long)rl * 256];
      hE1[g8 * 4 + j] = hcol[(long)(rl + 32) * 256];
    }

#define EPI(ACCU, ACCR, ACCXH, ACCHH, HE, RB)                               \
  _Pragma("unroll")                                                         \
  for (int g8 = 0; g8 < 4; ++g8) {                                          \
    _Pragma("unroll")                                                       \
    for (int j = 0; j < 4; ++j) {                                           \
      const int reg = g8 * 4 + j;                                           \
      const int rl  = (RB) + g8 * 8 + fq * 4 + j;                           \
      const float pu = ACCU[reg] + vbu;                                     \
      const float pr = ACCR[reg] + vbr;                                     \
      const float uu = __builtin_amdgcn_rcpf(1.f + __expf(-pu));            \
      const float rr = __builtin_amdgcn_rcpf(1.f + __expf(-pr));            \
      const float cc = fmaf(rr, ACCHH[reg], ACCXH[reg]) + vbh;              \
      const float tt = __builtin_amdgcn_rcpf(1.f + __expf(-2.f * cc));      \
      const float th = fmaf(2.f, tt, -1.f);                                 \
      const float uh = a_s[rl] * uu;                                        \
      const float h1v = HE[reg];                                            \
      ocol[(long)rl * 256] = fmaf(uh, th - h1v, h1v);                       \
    }                                                                       \
  }

  EPI(accU0, accR0, accXH0, accHH0, hE0, 0)
  EPI(accU1, accR1, accXH1, accHH1, hE1, 32)
#undef EPI
#undef TWRITE
#undef WOFF
}

extern "C" void kernel_launch(void* const* d_in, const int* in_sizes, int n_in,
                              void* d_out, int out_size, void* d_ws, size_t ws_size,
                              hipStream_t stream) {
  const float* x  = (const float*)d_in[0];
  const float* h1 = (const float*)d_in[1];
  const float* a  = (const float*)d_in[2];
  const float* Wu = (const float*)d_in[3];
  const float* Uu = (const float*)d_in[4];
  const float* bu = (const float*)d_in[5];
  const float* Wr = (const float*)d_in[6];
  const float* Ur = (const float*)d_in[7];
  const float* br = (const float*)d_in[8];
  const float* Wh = (const float*)d_in[9];
  const float* Uh = (const float*)d_in[10];
  const float* bh = (const float*)d_in[11];
  unsigned short* wt = (unsigned short*)d_ws;   // 16 slabs x 48 KB = 768 KB

  wprep<<<1536, 256, 0, stream>>>(Wu, Wr, Wh, Uu, Ur, Uh, wt);

  const int rows = in_sizes[0] / 256;           // 65536
  augru_main<<<rows / 64, 512, 0, stream>>>(x, h1, a, wt, bu, br, bh,
                                            (float*)d_out);
}